// Round 1
// baseline (320.347 us; speedup 1.0000x reference)
//
#include <hip/hip_runtime.h>
#include <math.h>

#define N_NODES 100000
#define N_EDGES 1600000
#define IN_DIM  256
#define HIDDEN  64

// ---------------------------------------------------------------------------
// K1: v[i] = sum_j W[i][j] * w2[j]  (collapse hidden dim of the GCN weight);
//     c = b . w2 + b2
// ---------------------------------------------------------------------------
__global__ void wv_kernel(const float* __restrict__ W, const float* __restrict__ b,
                          const float* __restrict__ w2, const float* __restrict__ b2,
                          float* __restrict__ v, float* __restrict__ c) {
    int i = threadIdx.x;  // 256 threads
    float acc = 0.f;
    #pragma unroll 8
    for (int j = 0; j < HIDDEN; ++j) acc += W[i * HIDDEN + j] * w2[j];
    v[i] = acc;
    if (i == 0) {
        float cc = b2[0];
        for (int j = 0; j < HIDDEN; ++j) cc += b[j] * w2[j];
        *c = cc;
    }
}

// ---------------------------------------------------------------------------
// K2: s[n] = x[n] . v   — one wave (64 lanes) per node, float4 per lane
//     (64 lanes x 16 B = exactly one 1 KiB row, perfectly coalesced)
// ---------------------------------------------------------------------------
__global__ void s_kernel(const float* __restrict__ x, const float* __restrict__ v,
                         float* __restrict__ s) {
    const int wave = threadIdx.x >> 6;
    const int lane = threadIdx.x & 63;
    const int n = blockIdx.x * 4 + wave;   // grid = 25000, 4 waves/block -> exactly N
    const float4* xr = (const float4*)(x + (size_t)n * IN_DIM);
    const float4* vr = (const float4*)v;
    float4 a  = xr[lane];
    float4 vv = vr[lane];
    float d = a.x * vv.x + a.y * vv.y + a.z * vv.z + a.w * vv.w;
    #pragma unroll
    for (int off = 32; off > 0; off >>= 1) d += __shfl_down(d, off, 64);
    if (lane == 0) s[n] = d;
}

// ---------------------------------------------------------------------------
// K3: in-degree count over dst (self-loop handled as +1 later)
// ---------------------------------------------------------------------------
__global__ void deg_kernel(const int* __restrict__ dst, int* __restrict__ cnt) {
    int e = blockIdx.x * blockDim.x + threadIdx.x;
    if (e < N_EDGES) atomicAdd(&cnt[dst[e]], 1);
}

// ---------------------------------------------------------------------------
// K4: dinv[n] = rsqrt(deg), t[n] = dinv[n] * s[n]  (hoist the src-side factor)
// ---------------------------------------------------------------------------
__global__ void dinv_kernel(const int* __restrict__ cnt, const float* __restrict__ s,
                            float* __restrict__ dinv, float* __restrict__ t) {
    int n = blockIdx.x * blockDim.x + threadIdx.x;
    if (n < N_NODES) {
        float di = rsqrtf((float)(cnt[n] + 1));   // +1 = self loop
        dinv[n] = di;
        t[n] = di * s[n];
    }
}

// ---------------------------------------------------------------------------
// K5: u[dst] += t[src]   — single-float atomic per edge; u is 400 KB (L2-hot)
// ---------------------------------------------------------------------------
__global__ void scatter_kernel(const int* __restrict__ src, const int* __restrict__ dst,
                               const float* __restrict__ t, float* __restrict__ u) {
    int e = blockIdx.x * blockDim.x + threadIdx.x;
    if (e < N_EDGES) atomicAdd(&u[dst[e]], t[src[e]]);
}

// ---------------------------------------------------------------------------
// K6: out[i] = sigmoid(dinv[i]*(u[i] + dinv[i]*s[i]) + c)
//     (dst-side dinv factor + self-loop dinv^2 term + folded bias)
// ---------------------------------------------------------------------------
__global__ void final_kernel(const float* __restrict__ dinv, const float* __restrict__ u,
                             const float* __restrict__ s, const float* __restrict__ c,
                             float* __restrict__ out) {
    int n = blockIdx.x * blockDim.x + threadIdx.x;
    if (n < N_NODES) {
        float di = dinv[n];
        float pre = di * (u[n] + di * s[n]) + c[0];
        out[n] = 1.f / (1.f + expf(-pre));
    }
}

extern "C" void kernel_launch(void* const* d_in, const int* in_sizes, int n_in,
                              void* d_out, int out_size, void* d_ws, size_t ws_size,
                              hipStream_t stream) {
    const float* x   = (const float*)d_in[0];   // [N, 256]
    const int*   ei  = (const int*)  d_in[1];   // [2, E] row-major: src then dst
    const float* W   = (const float*)d_in[2];   // [256, 64]
    const float* b   = (const float*)d_in[3];   // [64]
    const float* w2  = (const float*)d_in[4];   // [64]
    const float* b2  = (const float*)d_in[5];   // [1]
    float* out = (float*)d_out;

    const int* src = ei;
    const int* dst = ei + N_EDGES;

    // workspace layout (float offsets)
    float* ws   = (float*)d_ws;
    float* v    = ws;             // 256
    float* c    = ws + 256;       // 1
    float* s    = ws + 1024;      // 100000
    float* t    = ws + 102400;    // 100000
    float* dinv = ws + 204800;    // 100000
    float* u    = ws + 307200;    // 100000  (zeroed)
    int*   cnt  = (int*)(ws + 407200); // 100000 (zeroed, adjacent to u)

    // zero u + cnt in one async memset (ws is poisoned 0xAA before every call)
    hipMemsetAsync((char*)d_ws + (size_t)307200 * 4, 0, (size_t)200000 * 4, stream);

    wv_kernel<<<1, 256, 0, stream>>>(W, b, w2, b2, v, c);
    s_kernel<<<N_NODES / 4, 256, 0, stream>>>(x, v, s);
    deg_kernel<<<(N_EDGES + 255) / 256, 256, 0, stream>>>(dst, cnt);
    dinv_kernel<<<(N_NODES + 255) / 256, 256, 0, stream>>>(cnt, s, dinv, t);
    scatter_kernel<<<(N_EDGES + 255) / 256, 256, 0, stream>>>(src, dst, t, u);
    final_kernel<<<(N_NODES + 255) / 256, 256, 0, stream>>>(dinv, u, s, c, out);
}